// Round 4
// baseline (8200.620 us; speedup 1.0000x reference)
//
#include <hip/hip_runtime.h>

typedef __attribute__((ext_vector_type(8))) short short8;
typedef __attribute__((ext_vector_type(4))) float f32x4;
typedef __attribute__((ext_vector_type(4))) int   i32x4;
typedef __attribute__((ext_vector_type(4))) float fvec4;
typedef __attribute__((ext_vector_type(4))) unsigned short u16x4;

#define B_ 64
#define T_ 256
#define H_ 512
#define NG 2048   // 4*H
#define BTH (64*256*512)
#define BH (64*512)
#define NK ((size_t)NG * H_)

__device__ __forceinline__ float bf2f(unsigned short u) {
    return __builtin_bit_cast(float, ((unsigned)u) << 16);
}
__device__ __forceinline__ unsigned short f2bf(float f) {
    unsigned u = __builtin_bit_cast(unsigned, f);
    u += 0x7fffu + ((u >> 16) & 1u);   // RNE
    return (unsigned short)(u >> 16);
}
__device__ __forceinline__ float sigm(float x) { return 1.f / (1.f + __expf(-x)); }
__device__ __forceinline__ float tanh_f(float x) {
    x = fminf(15.f, fmaxf(-15.f, x));
    float e = __expf(-2.f * x);
    return (1.f - e) / (1.f + e);
}

// ---- coherent-point (L3) accesses via relaxed agent-scope atomics ----
__device__ __forceinline__ short8 load_frag_coh(const unsigned* p) {
    i32x4 w;
    w[0] = (int)__hip_atomic_load(p + 0, __ATOMIC_RELAXED, __HIP_MEMORY_SCOPE_AGENT);
    w[1] = (int)__hip_atomic_load(p + 1, __ATOMIC_RELAXED, __HIP_MEMORY_SCOPE_AGENT);
    w[2] = (int)__hip_atomic_load(p + 2, __ATOMIC_RELAXED, __HIP_MEMORY_SCOPE_AGENT);
    w[3] = (int)__hip_atomic_load(p + 3, __ATOMIC_RELAXED, __HIP_MEMORY_SCOPE_AGENT);
    return __builtin_bit_cast(short8, w);
}
__device__ __forceinline__ void store_coh(unsigned* p, unsigned v) {
    __hip_atomic_store(p, v, __ATOMIC_RELAXED, __HIP_MEMORY_SCOPE_AGENT);
}

// ---------------- prep: weight transpose f32[K,N] -> bf16[N,K] ----------------
__global__ void transpose_cvt(const float* __restrict__ Wi, const float* __restrict__ Wh,
                              unsigned short* __restrict__ Wt) {
    __shared__ float tile[64][65];
    int z = blockIdx.z;
    const float* src = (z < 2 ? Wi : Wh) + (size_t)(z & 1) * H_ * NG;
    unsigned short* dst = Wt + (size_t)z * NG * H_;
    int k0 = blockIdx.x * 64, n0 = blockIdx.y * 64;
    int tx = threadIdx.x & 63, ty = threadIdx.x >> 6;
#pragma unroll
    for (int p = 0; p < 16; ++p) {
        int r = (p << 2) + ty;
        tile[r][tx] = src[(size_t)(k0 + r) * NG + n0 + tx];
    }
    __syncthreads();
#pragma unroll
    for (int p = 0; p < 16; ++p) {
        int r = (p << 2) + ty;
        dst[(size_t)(n0 + r) * H_ + k0 + tx] = f2bf(tile[tx][r]);
    }
}

__global__ void cvt_bf16(const float* __restrict__ x, unsigned short* __restrict__ xb) {
    size_t i = ((size_t)blockIdx.x * 256 + threadIdx.x) * 4;
    fvec4 v = *(const fvec4*)&x[i];
    u16x4 o;
    o[0] = f2bf(v[0]); o[1] = f2bf(v[1]); o[2] = f2bf(v[2]); o[3] = f2bf(v[3]);
    *(u16x4*)&xb[i] = o;
}

// ---------------- big GEMM: Gi[t][b][4H] = A @ Wt^T + bias1 + bias2 (bf16 out) ----------
__global__ __launch_bounds__(256) void gemm_bt(
    const unsigned short* __restrict__ A, const unsigned short* __restrict__ Bt,
    const float* __restrict__ bias1, const float* __restrict__ bias2,
    unsigned short* __restrict__ C) {
    const int tid = threadIdx.x;
    const int wave = tid >> 6, lane = tid & 63;
    const int quad = lane >> 4, l15 = lane & 15;
    const int row0 = blockIdx.x * 64 + wave * 16;
    const int col0 = blockIdx.y * 64;
    f32x4 acc[4] = {};
    const unsigned short* ap = A + (size_t)(row0 + l15) * H_ + (quad << 3);
    const unsigned short* bp = Bt + (size_t)(col0 + l15) * H_ + (quad << 3);
#pragma unroll
    for (int kk = 0; kk < H_; kk += 32) {
        short8 a = *(const short8*)(ap + kk);
#pragma unroll
        for (int c4 = 0; c4 < 4; ++c4) {
            short8 b = *(const short8*)(bp + (size_t)(c4 << 4) * H_ + kk);
            acc[c4] = __builtin_amdgcn_mfma_f32_16x16x32_bf16(a, b, acc[c4], 0, 0, 0);
        }
    }
#pragma unroll
    for (int c4 = 0; c4 < 4; ++c4) {
        int col = col0 + (c4 << 4) + l15;
        float bs = bias1[col] + bias2[col];
#pragma unroll
        for (int r = 0; r < 4; ++r) {
            int row = row0 + (quad << 2) + r;
            int t = row & 255, b = row >> 8;
            C[((size_t)t * B_ + b) * NG + col] = f2bf(acc[c4][r] + bs);
        }
    }
}

// ---------------- flag-array grid barrier: no RMW, no sleep, parallel poll ----------
// Arrival: WG stores phase number to its own 64B-spaced slot (after syncthreads
// drains vmcnt -> all sc1 h-stores are at the coherent point first).
// Wait: wave 0, lane i polls slot i; ballot loop until all 64 slots >= want.
__device__ __forceinline__ void fbar(unsigned* flags, int wg, unsigned want, int tid) {
    __syncthreads();
    if (tid == 0)
        __hip_atomic_store(&flags[wg << 4], want, __ATOMIC_RELAXED, __HIP_MEMORY_SCOPE_AGENT);
    asm volatile("" ::: "memory");   // pin store before poll loop
    if (tid < 64) {
        int spins = 0;
        unsigned v;
        do {
            v = __hip_atomic_load(&flags[tid << 4], __ATOMIC_RELAXED, __HIP_MEMORY_SCOPE_AGENT);
        } while (__ballot(v < want) != 0ull && ++spins < 150000);  // failsafe, no hang
    }
    __syncthreads();
}

// ---------------- fused persistent 2-layer LSTM ----------------
// 64 WGs x 256 thr. WGs 0-31: layer 0; WGs 32-63: layer 1 (pipelined 1 step behind).
// Phase t (0..256): L0 computes h0(t) [t<256]; L1 computes h1(t-1) [t>=1] from
// h0(t-1)@Wi1 + h1(t-2)@Wh1 (K=1024). One everyone-barrier per phase.
// h exchanged via L3 (u32-packed relaxed agent atomics), double-buffered by parity.
// Weights streamed from L2 each step (opaque pointer prevents hoist/spill).
__global__ __launch_bounds__(256, 1) void lstm_fused(
    const unsigned short* __restrict__ Gi0,  // [T][B][2048] bf16 (bias included)
    const unsigned short* __restrict__ Wt,   // 4 slabs [2048][512]: Wi0,Wi1,Wh0,Wh1
    const float* __restrict__ bi, const float* __restrict__ bh,  // [2][2048]
    unsigned* __restrict__ h0buf,            // [2][64][256] u32-packed bf16 pairs
    unsigned* __restrict__ h1buf,            // [2][64][256]
    float* __restrict__ out,                 // outs | hT[2] | cT[2]
    unsigned* __restrict__ flags) {
    const int tid = threadIdx.x;
    const int wave = tid >> 6, lane = tid & 63;
    const int quad = lane >> 4, l15 = lane & 15;
    const int wg = blockIdx.x;
    const bool isL1 = wg >= 32;
    const int j0 = (wg & 31) << 4;
    const int m0 = wave << 4;
    const int jj = j0 + l15;

    float* hT = out + BTH;
    float* cT = out + BTH + 2 * BH;

    // zero my parity-1 exchange slice (h(t=-1) = 0)
    {
        unsigned* zb = (isL1 ? h1buf : h0buf) + 16384;
        if (!(l15 & 1)) {
#pragma unroll
            for (int r = 0; r < 4; ++r) {
                int b = m0 + (quad << 2) + r;
                store_coh(&zb[(b << 8) + (jj >> 1)], 0u);
            }
        }
    }

    float cc[4] = {0.f, 0.f, 0.f, 0.f};
    float gv[4][4];
    float bs[4];
    if (!isL1) {
        // prefetch Gi0[t=0]
#pragma unroll
        for (int r = 0; r < 4; ++r) {
            int b = m0 + (quad << 2) + r;
#pragma unroll
            for (int g = 0; g < 4; ++g)
                gv[g][r] = bf2f(Gi0[(size_t)b * NG + (g << 9) + jj]);
        }
    } else {
#pragma unroll
        for (int g = 0; g < 4; ++g)
            bs[g] = bi[NG + (g << 9) + jj] + bh[NG + (g << 9) + jj];
    }

    fbar(flags, wg, 1u, tid);

    for (int t = 0; t <= T_; ++t) {
        if (!isL1) {
            if (t < T_) {
                const unsigned* hp = h0buf + (((t + 1) & 1) << 14);  // h0(t-1)
                unsigned* hn = h0buf + ((t & 1) << 14);              // h0(t)
                const unsigned short* wp = Wt + 2 * NK;              // Wh0
                asm volatile("" : "+v"(wp));                         // stream from L2 each step

                const unsigned* ap = hp + ((m0 + l15) << 8) + (quad << 2);
                short8 ha[16];
#pragma unroll
                for (int kb = 0; kb < 16; ++kb) ha[kb] = load_frag_coh(ap + (kb << 4));

                f32x4 acc[4] = {};
#pragma unroll
                for (int kb = 0; kb < 16; ++kb)
#pragma unroll
                    for (int g = 0; g < 4; ++g)
                        acc[g] = __builtin_amdgcn_mfma_f32_16x16x32_bf16(
                            ha[kb],
                            *(const short8*)&wp[(size_t)((g << 9) + jj) * H_ + (kb << 5) + (quad << 3)],
                            acc[g], 0, 0, 0);

#pragma unroll
                for (int r = 0; r < 4; ++r) {
                    int b = m0 + (quad << 2) + r;
                    float iv = sigm(acc[0][r] + gv[0][r]);
                    float fv = sigm(acc[1][r] + gv[1][r]);
                    float gg = tanh_f(acc[2][r] + gv[2][r]);
                    float ov = sigm(acc[3][r] + gv[3][r]);
                    float cn = fv * cc[r] + iv * gg;
                    cc[r] = cn;
                    float hv = ov * tanh_f(cn);
                    unsigned short hb16 = f2bf(hv);
                    unsigned packed = (unsigned)hb16 |
                                      (((unsigned)(unsigned short)__shfl_xor((int)hb16, 1)) << 16);
                    if (!(l15 & 1)) store_coh(&hn[(b << 8) + (jj >> 1)], packed);
                    if (t == T_ - 1) {
                        hT[((size_t)b << 9) + jj] = hv;
                        cT[((size_t)b << 9) + jj] = cn;
                    }
                }

                // prefetch Gi0[t+1] before the barrier
                int tn = (t + 1) & (T_ - 1);
                float gn[4][4];
#pragma unroll
                for (int r = 0; r < 4; ++r) {
                    int b = m0 + (quad << 2) + r;
#pragma unroll
                    for (int g = 0; g < 4; ++g)
                        gn[g][r] = bf2f(Gi0[((size_t)tn * B_ + b) * NG + (g << 9) + jj]);
                }
                fbar(flags, wg, (unsigned)(t + 2), tid);
#pragma unroll
                for (int r = 0; r < 4; ++r)
#pragma unroll
                    for (int g = 0; g < 4; ++g) gv[g][r] = gn[g][r];
                continue;
            }
        } else {
            if (t >= 1) {
                int s = t - 1;
                const unsigned* hp0 = h0buf + (((t - 1) & 1) << 14);  // h0(s)
                const unsigned* hp1 = h1buf + ((t & 1) << 14);        // h1(s-1)
                unsigned* hn1 = h1buf + (((t - 1) & 1) << 14);        // h1(s)
                const unsigned short* wi = Wt + 1 * NK;               // Wi1
                const unsigned short* wh = Wt + 3 * NK;               // Wh1
                asm volatile("" : "+v"(wi));
                asm volatile("" : "+v"(wh));

                const unsigned* ap0 = hp0 + ((m0 + l15) << 8) + (quad << 2);
                const unsigned* ap1 = hp1 + ((m0 + l15) << 8) + (quad << 2);
                short8 ha0[16], ha1[16];
#pragma unroll
                for (int kb = 0; kb < 16; ++kb) ha0[kb] = load_frag_coh(ap0 + (kb << 4));
#pragma unroll
                for (int kb = 0; kb < 16; ++kb) ha1[kb] = load_frag_coh(ap1 + (kb << 4));

                f32x4 acc[4] = {};
#pragma unroll
                for (int kb = 0; kb < 16; ++kb)
#pragma unroll
                    for (int g = 0; g < 4; ++g)
                        acc[g] = __builtin_amdgcn_mfma_f32_16x16x32_bf16(
                            ha0[kb],
                            *(const short8*)&wi[(size_t)((g << 9) + jj) * H_ + (kb << 5) + (quad << 3)],
                            acc[g], 0, 0, 0);
#pragma unroll
                for (int kb = 0; kb < 16; ++kb)
#pragma unroll
                    for (int g = 0; g < 4; ++g)
                        acc[g] = __builtin_amdgcn_mfma_f32_16x16x32_bf16(
                            ha1[kb],
                            *(const short8*)&wh[(size_t)((g << 9) + jj) * H_ + (kb << 5) + (quad << 3)],
                            acc[g], 0, 0, 0);

#pragma unroll
                for (int r = 0; r < 4; ++r) {
                    int b = m0 + (quad << 2) + r;
                    float iv = sigm(acc[0][r] + bs[0]);
                    float fv = sigm(acc[1][r] + bs[1]);
                    float gg = tanh_f(acc[2][r] + bs[2]);
                    float ov = sigm(acc[3][r] + bs[3]);
                    float cn = fv * cc[r] + iv * gg;
                    cc[r] = cn;
                    float hv = ov * tanh_f(cn);
                    unsigned short hb16 = f2bf(hv);
                    unsigned packed = (unsigned)hb16 |
                                      (((unsigned)(unsigned short)__shfl_xor((int)hb16, 1)) << 16);
                    if (!(l15 & 1)) store_coh(&hn1[(b << 8) + (jj >> 1)], packed);
                    out[((size_t)(b << 8) + s) * H_ + jj] = hv;
                    if (s == T_ - 1) {
                        hT[BH + ((size_t)b << 9) + jj] = hv;
                        cT[BH + ((size_t)b << 9) + jj] = cn;
                    }
                }
                fbar(flags, wg, (unsigned)(t + 2), tid);
                continue;
            }
        }
        // inactive this phase: just the barrier
        fbar(flags, wg, (unsigned)(t + 2), tid);
    }
}

extern "C" void kernel_launch(void* const* d_in, const int* in_sizes, int n_in,
                              void* d_out, int out_size, void* d_ws, size_t ws_size,
                              hipStream_t stream) {
    const float* x  = (const float*)d_in[0];
    const float* Wi = (const float*)d_in[1];
    const float* Wh = (const float*)d_in[2];
    const float* bi = (const float*)d_in[3];
    const float* bh = (const float*)d_in[4];
    float* out = (float*)d_out;

    char* w = (char*)d_ws;
    unsigned short* Wt = (unsigned short*)w;                      // 8 MB
    unsigned short* xb = Wt + 4 * NK;                             // 16 MB
    unsigned short* Gi = xb + (size_t)16384 * H_;                 // 64 MB
    unsigned* h0buf    = (unsigned*)(Gi + (size_t)16384 * NG);    // 128 KB
    unsigned* h1buf    = h0buf + 2 * 16384;                       // 128 KB
    unsigned* flags    = h1buf + 2 * 16384;                       // 4 KB

    hipMemsetAsync(flags, 0, 4096, stream);

    transpose_cvt<<<dim3(8, 32, 4), 256, 0, stream>>>(Wi, Wh, Wt);
    cvt_bf16<<<8192, 256, 0, stream>>>(x, xb);
    gemm_bt<<<dim3(256, 32), 256, 0, stream>>>(xb, Wt + 0 * NK, bi, bh, Gi);
    lstm_fused<<<64, 256, 0, stream>>>(Gi, Wt, bi, bh, h0buf, h1buf, out, flags);
}

// Round 5
// 5595.015 us; speedup vs baseline: 1.4657x; 1.4657x over previous
//
#include <hip/hip_runtime.h>

typedef __attribute__((ext_vector_type(8))) short short8;
typedef __attribute__((ext_vector_type(4))) float f32x4;
typedef __attribute__((ext_vector_type(4))) int   i32x4;
typedef __attribute__((ext_vector_type(4))) float fvec4;
typedef __attribute__((ext_vector_type(4))) unsigned short u16x4;

#define B_ 64
#define T_ 256
#define H_ 512
#define NG 2048   // 4*H
#define BTH (64*256*512)
#define BH (64*512)
#define NK ((size_t)NG * H_)

__device__ __forceinline__ float bf2f(unsigned short u) {
    return __builtin_bit_cast(float, ((unsigned)u) << 16);
}
__device__ __forceinline__ unsigned short f2bf(float f) {
    unsigned u = __builtin_bit_cast(unsigned, f);
    u += 0x7fffu + ((u >> 16) & 1u);   // RNE
    return (unsigned short)(u >> 16);
}
__device__ __forceinline__ float sigm(float x) { return 1.f / (1.f + __expf(-x)); }
__device__ __forceinline__ float tanh_f(float x) {
    x = fminf(15.f, fmaxf(-15.f, x));
    float e = __expf(-2.f * x);
    return (1.f - e) / (1.f + e);
}

// ---- coherent-point (L3) accesses via relaxed agent-scope atomics ----
__device__ __forceinline__ short8 load_frag_coh(const unsigned* p) {
    i32x4 w;
    w[0] = (int)__hip_atomic_load(p + 0, __ATOMIC_RELAXED, __HIP_MEMORY_SCOPE_AGENT);
    w[1] = (int)__hip_atomic_load(p + 1, __ATOMIC_RELAXED, __HIP_MEMORY_SCOPE_AGENT);
    w[2] = (int)__hip_atomic_load(p + 2, __ATOMIC_RELAXED, __HIP_MEMORY_SCOPE_AGENT);
    w[3] = (int)__hip_atomic_load(p + 3, __ATOMIC_RELAXED, __HIP_MEMORY_SCOPE_AGENT);
    return __builtin_bit_cast(short8, w);
}
__device__ __forceinline__ void store_coh(unsigned* p, unsigned v) {
    __hip_atomic_store(p, v, __ATOMIC_RELAXED, __HIP_MEMORY_SCOPE_AGENT);
}
__device__ __forceinline__ void vm_drain() {
    asm volatile("s_waitcnt vmcnt(0)" ::: "memory");
}

// ---------------- prep: weight transpose f32[K,N] -> bf16[N,K] ----------------
__global__ void transpose_cvt(const float* __restrict__ Wi, const float* __restrict__ Wh,
                              unsigned short* __restrict__ Wt) {
    __shared__ float tile[64][65];
    int z = blockIdx.z;
    const float* src = (z < 2 ? Wi : Wh) + (size_t)(z & 1) * H_ * NG;
    unsigned short* dst = Wt + (size_t)z * NG * H_;
    int k0 = blockIdx.x * 64, n0 = blockIdx.y * 64;
    int tx = threadIdx.x & 63, ty = threadIdx.x >> 6;
#pragma unroll
    for (int p = 0; p < 16; ++p) {
        int r = (p << 2) + ty;
        tile[r][tx] = src[(size_t)(k0 + r) * NG + n0 + tx];
    }
    __syncthreads();
#pragma unroll
    for (int p = 0; p < 16; ++p) {
        int r = (p << 2) + ty;
        dst[(size_t)(n0 + r) * H_ + k0 + tx] = f2bf(tile[tx][r]);
    }
}

__global__ void cvt_bf16(const float* __restrict__ x, unsigned short* __restrict__ xb) {
    size_t i = ((size_t)blockIdx.x * 256 + threadIdx.x) * 4;
    fvec4 v = *(const fvec4*)&x[i];
    u16x4 o;
    o[0] = f2bf(v[0]); o[1] = f2bf(v[1]); o[2] = f2bf(v[2]); o[3] = f2bf(v[3]);
    *(u16x4*)&xb[i] = o;
}

// ---------------- big GEMM: Gi[t][b][4H] = A @ Wt^T + bias1 + bias2 (bf16 out) ----------
__global__ __launch_bounds__(256) void gemm_bt(
    const unsigned short* __restrict__ A, const unsigned short* __restrict__ Bt,
    const float* __restrict__ bias1, const float* __restrict__ bias2,
    unsigned short* __restrict__ C) {
    const int tid = threadIdx.x;
    const int wave = tid >> 6, lane = tid & 63;
    const int quad = lane >> 4, l15 = lane & 15;
    const int row0 = blockIdx.x * 64 + wave * 16;
    const int col0 = blockIdx.y * 64;
    f32x4 acc[4] = {};
    const unsigned short* ap = A + (size_t)(row0 + l15) * H_ + (quad << 3);
    const unsigned short* bp = Bt + (size_t)(col0 + l15) * H_ + (quad << 3);
#pragma unroll
    for (int kk = 0; kk < H_; kk += 32) {
        short8 a = *(const short8*)(ap + kk);
#pragma unroll
        for (int c4 = 0; c4 < 4; ++c4) {
            short8 b = *(const short8*)(bp + (size_t)(c4 << 4) * H_ + kk);
            acc[c4] = __builtin_amdgcn_mfma_f32_16x16x32_bf16(a, b, acc[c4], 0, 0, 0);
        }
    }
#pragma unroll
    for (int c4 = 0; c4 < 4; ++c4) {
        int col = col0 + (c4 << 4) + l15;
        float bs = bias1[col] + bias2[col];
#pragma unroll
        for (int r = 0; r < 4; ++r) {
            int row = row0 + (quad << 2) + r;
            int t = row & 255, b = row >> 8;
            C[((size_t)t * B_ + b) * NG + col] = f2bf(acc[c4][r] + bs);
        }
    }
}

// ---------------- persistent recurrent kernel, publish-flag sync ----------------
// 32 WGs x 256 thr. WG owns gate cols [j0,j0+16) of all 4 gates.
// Wh slice (64 KB) LDS-resident. h exchanged via L3 (u32-packed relaxed agent
// atomics), double-buffered by step parity. Sync: flag[w] = #h-publishes by WG w;
// consumers poll all 32 flags (skew-tolerant, no convoy). Publishing h(t+1)
// implies WG w finished READING h(t), so 2 buffers suffice.
__global__ __launch_bounds__(256, 1) void lstm_rec(
    const unsigned short* __restrict__ Gi,   // [T][B][2048] bf16 (bias included)
    const unsigned short* __restrict__ Wt,   // Wh^T [2048][512] bf16
    unsigned* __restrict__ hb0, unsigned* __restrict__ hb1,  // u32-packed [64][256]
    unsigned short* __restrict__ out_bf,     // layer0: [b*T+t][512] bf16 (or null)
    float* __restrict__ out_f,               // layer1: [B][T][512] f32 (or null)
    float* __restrict__ hT, float* __restrict__ cT,
    unsigned* __restrict__ flags) {
    __shared__ unsigned short wlds[64 * 512];   // 64 KB: frag f=(kb*4+g) at [f*512 + lane*8]
    const int tid = threadIdx.x;
    const int wave = tid >> 6, lane = tid & 63;
    const int quad = lane >> 4, l15 = lane & 15;
    const int wg = blockIdx.x;
    const int j0 = wg << 4;
    const int m0 = wave << 4;
    const int jj = j0 + l15;

    // ---- stage Wh slice into LDS (one-time): frag f assigned to wave f&3 ----
    for (int f = wave; f < 64; f += 4) {
        int kb = f >> 2, g = f & 3;
        short8 w = *(const short8*)&Wt[(size_t)((g << 9) + jj) * H_ + (kb << 5) + (quad << 3)];
        *(short8*)&wlds[f * 512 + lane * 8] = w;
    }

    // ---- zero own h(t=-1) slice (read by step 0 from hb0) ----
    if (!(l15 & 1)) {
#pragma unroll
        for (int r = 0; r < 4; ++r) {
            int b = m0 + (quad << 2) + r;
            store_coh(&hb0[(b << 8) + (jj >> 1)], 0u);
        }
    }
    float cc[4] = {0.f, 0.f, 0.f, 0.f};

    // ---- prefetch Gi[0] ----
    float gv[4][4];
#pragma unroll
    for (int r = 0; r < 4; ++r) {
        int b = m0 + (quad << 2) + r;
#pragma unroll
        for (int g = 0; g < 4; ++g)
            gv[g][r] = bf2f(Gi[(size_t)b * NG + (g << 9) + jj]);
    }
    vm_drain();          // zero-stores at L3, weight loads done
    __syncthreads();     // LDS weights visible to all waves
    if (tid == 0) store_coh(&flags[wg << 4], 1u);   // publish #0 (the zeros)
    asm volatile("" ::: "memory");

    for (int t = 0; t < T_; ++t) {
        // ---- wait for all producers to have published h(t-1) (flag >= t+1) ----
        {
            unsigned want = (unsigned)(t + 1);
            int spins = 0;
            unsigned v;
            do {
                v = (lane < 32)
                        ? __hip_atomic_load(&flags[lane << 4], __ATOMIC_RELAXED,
                                            __HIP_MEMORY_SCOPE_AGENT)
                        : want;
                if (__ballot(v < want) == 0ull) break;
                __builtin_amdgcn_s_sleep(1);
            } while (++spins < 200000);   // failsafe: no hang
        }
        asm volatile("" ::: "memory");

        const unsigned* hp = (t & 1) ? hb1 : hb0;
        unsigned* hn = (t & 1) ? hb0 : hb1;

        // ---- A-fragments of h(t-1) from L3 ----
        const unsigned* ap = hp + ((m0 + l15) << 8) + (quad << 2);
        short8 ha[16];
#pragma unroll
        for (int kb = 0; kb < 16; ++kb) ha[kb] = load_frag_coh(ap + (kb << 4));

        // ---- MFMA loop, B-frags from LDS ----
        f32x4 acc0 = {}, acc1 = {}, acc2 = {}, acc3 = {};
#pragma unroll
        for (int kb = 0; kb < 16; ++kb) {
            short8 b0 = *(const short8*)&wlds[(kb * 4 + 0) * 512 + lane * 8];
            short8 b1 = *(const short8*)&wlds[(kb * 4 + 1) * 512 + lane * 8];
            short8 b2 = *(const short8*)&wlds[(kb * 4 + 2) * 512 + lane * 8];
            short8 b3 = *(const short8*)&wlds[(kb * 4 + 3) * 512 + lane * 8];
            acc0 = __builtin_amdgcn_mfma_f32_16x16x32_bf16(ha[kb], b0, acc0, 0, 0, 0);
            acc1 = __builtin_amdgcn_mfma_f32_16x16x32_bf16(ha[kb], b1, acc1, 0, 0, 0);
            acc2 = __builtin_amdgcn_mfma_f32_16x16x32_bf16(ha[kb], b2, acc2, 0, 0, 0);
            acc3 = __builtin_amdgcn_mfma_f32_16x16x32_bf16(ha[kb], b3, acc3, 0, 0, 0);
        }

        // ---- nonlinearity + state update + stores ----
#pragma unroll
        for (int r = 0; r < 4; ++r) {
            int b = m0 + (quad << 2) + r;
            float iv = sigm(acc0[r] + gv[0][r]);
            float fv = sigm(acc1[r] + gv[1][r]);
            float gg = tanh_f(acc2[r] + gv[2][r]);
            float ov = sigm(acc3[r] + gv[3][r]);
            float cn = fv * cc[r] + iv * gg;
            cc[r] = cn;
            float hv = ov * tanh_f(cn);
            unsigned short hb16 = f2bf(hv);
            unsigned packed = (unsigned)hb16 |
                              (((unsigned)(unsigned short)__shfl_xor((int)hb16, 1)) << 16);
            if (!(l15 & 1)) store_coh(&hn[(b << 8) + (jj >> 1)], packed);
            if (out_bf) out_bf[((size_t)(b << 8) + t) * H_ + jj] = hb16;
            if (out_f) out_f[((size_t)(b << 8) + t) * H_ + jj] = hv;
            if (t == T_ - 1) {
                hT[((size_t)b << 9) + jj] = hv;
                cT[((size_t)b << 9) + jj] = cn;
            }
        }

        // ---- publish: drain my stores, ensure all waves done, raise flag ----
        vm_drain();
        __syncthreads();
        if (tid == 0) store_coh(&flags[wg << 4], (unsigned)(t + 2));
        asm volatile("" ::: "memory");

        // ---- NOW prefetch Gi[t+1]: overlaps other WGs' publish + next k-loop ----
        int tn = (t + 1) & (T_ - 1);
#pragma unroll
        for (int r = 0; r < 4; ++r) {
            int b = m0 + (quad << 2) + r;
#pragma unroll
            for (int g = 0; g < 4; ++g)
                gv[g][r] = bf2f(Gi[((size_t)tn * B_ + b) * NG + (g << 9) + jj]);
        }
    }
}

extern "C" void kernel_launch(void* const* d_in, const int* in_sizes, int n_in,
                              void* d_out, int out_size, void* d_ws, size_t ws_size,
                              hipStream_t stream) {
    const float* x  = (const float*)d_in[0];
    const float* Wi = (const float*)d_in[1];
    const float* Wh = (const float*)d_in[2];
    const float* bi = (const float*)d_in[3];
    const float* bh = (const float*)d_in[4];
    float* out = (float*)d_out;

    char* w = (char*)d_ws;
    unsigned short* Wt    = (unsigned short*)w;                 // 8 MB
    unsigned short* xb    = Wt + 4 * NK;                        // 16 MB
    unsigned short* out0b = xb + (size_t)16384 * H_;            // 16 MB
    unsigned short* Gi    = out0b + (size_t)16384 * H_;         // 64 MB
    unsigned* h0          = (unsigned*)(Gi + (size_t)16384 * NG);  // 64 KB
    unsigned* h1          = h0 + (BH / 2);                      // 64 KB
    unsigned* flags       = h1 + (BH / 2);                      // 2x 2 KB

    hipMemsetAsync(flags, 0, 8192, stream);

    transpose_cvt<<<dim3(8, 32, 4), 256, 0, stream>>>(Wi, Wh, Wt);
    cvt_bf16<<<8192, 256, 0, stream>>>(x, xb);

    // ---- layer 0 ----
    gemm_bt<<<dim3(256, 32), 256, 0, stream>>>(xb, Wt + 0 * NK, bi, bh, Gi);
    lstm_rec<<<32, 256, 0, stream>>>(Gi, Wt + 2 * NK, h0, h1,
                                     out0b, nullptr,
                                     out + BTH + 0 * BH, out + BTH + 2 * BH + 0 * BH, flags);
    // ---- layer 1 ----
    gemm_bt<<<dim3(256, 32), 256, 0, stream>>>(out0b, Wt + 1 * NK, bi + NG, bh + NG, Gi);
    lstm_rec<<<32, 256, 0, stream>>>(Gi, Wt + 3 * NK, h0, h1,
                                     nullptr, out,
                                     out + BTH + 1 * BH, out + BTH + 2 * BH + 1 * BH,
                                     flags + 512);
}